// Round 1
// baseline (460.926 us; speedup 1.0000x reference)
//
#include <hip/hip_runtime.h>
#include <hip/hip_bf16.h>

// TemporalAttentionWithDecay, MI355X gfx950.
// B=4, N=1024, T=32, C=256, H=8, d=32, BN=4096. All fp32 in/out.
// Strategy: fully fused per-(2×bn) block; bf16 MFMA 16x16x32 for all GEMMs;
// LN/softmax/sigmoid/residual in fp32. Weights pre-converted to bf16
// B-fragment-linear layout in d_ws by a prep kernel.

typedef __attribute__((ext_vector_type(8))) short  s16x8;   // 8 bf16 = 4 VGPR
typedef __attribute__((ext_vector_type(4))) float  f32x4;   // MFMA acc
typedef __attribute__((ext_vector_type(4))) unsigned short us16x4;

#define MFMA16(a, b, c) __builtin_amdgcn_mfma_f32_16x16x32_bf16((a), (b), (c), 0, 0, 0)

static __device__ __forceinline__ short f2bf(float f) {
  union { float f; unsigned u; } v; v.f = f;
  unsigned r = (v.u + 0x7FFFu + ((v.u >> 16) & 1u)) >> 16;  // RNE
  return (short)r;
}

// ---- LDS layout (bytes). Row stride 528 B (=256 bf16 + 16 B pad): row starts
// step 4 banks -> 8 distinct starts -> 2-way conflict (free) on ds_read_b128.
#define RS      528
#define VTS     80        // 32 bf16 + 16 B pad rows (vT, P)
#define LDS_H   0         // h  bf16 [64][RS]          33792
#define LDS_Q   33792     // q, later g*o              33792
#define LDS_K   67584     // k                         33792
#define LDS_VT  101376    // vT bf16 [2][256][VTS]     40960
#define LDS_TS  142336    // timestamps f32 [32]       128
#define LDS_TOTAL 142464
// P buffers overlay dead h region: per-wave 32*VTS = 2560 B at w*2560 (max 20480 < 33792)

// ---- ws layout (bytes): 5 weight matrices in B-fragment-linear bf16, then lambda.
// Fragment (nt, ks, lane, i) holds W[j=16*nt+(lane&15)][c=32*ks+8*(lane>>4)+i].
#define WS_WQ   0
#define WS_WK   131072
#define WS_WV   262144
#define WS_WG   393216
#define WS_WO   524288
#define WS_LAM  655360
#define WS_NEED 655392

__global__ void prep_kernel(const float* __restrict__ Wq, const float* __restrict__ Wk,
                            const float* __restrict__ Wv, const float* __restrict__ Wg,
                            const float* __restrict__ Wo, const float* __restrict__ ll,
                            char* __restrict__ ws) {
  int tid = blockIdx.x * 256 + threadIdx.x;
  if (tid < 5 * 8192) {
    int m      = tid >> 13;
    int within = tid & 8191;
    int lane   = within & 63;
    int j = 16 * (within >> 9) + (lane & 15);
    int c = 32 * ((within >> 6) & 7) + 8 * (lane >> 4);
    const float* W = (m == 0) ? Wq : (m == 1) ? Wk : (m == 2) ? Wv : (m == 3) ? Wg : Wo;
    const float* src = W + j * 256 + c;
    s16x8 o;
#pragma unroll
    for (int i = 0; i < 8; ++i) o[i] = f2bf(src[i]);
    *(s16x8*)(ws + (size_t)tid * 16) = o;  // m*131072 + within*16 == tid*16
  } else if (tid < 5 * 8192 + 8) {
    ((float*)(ws + WS_LAM))[tid - 40960] = __expf(ll[tid - 40960]);
  }
}

// One K-block GEMM: D[64 x 32cols-of-wave] += A(lds rows, bf16) * Wfrag.
static __device__ __forceinline__ void gemm32(const char* lds, int aoff,
                                              const char* wsb, int w, int lane,
                                              f32x4 acc[4][2]) {
  const int l15 = lane & 15, l4 = lane >> 4;
  const s16x8* Bf = (const s16x8*)wsb + (2 * w * 8) * 64 + lane;
#pragma unroll
  for (int ks = 0; ks < 8; ++ks) {
    s16x8 a[4];
#pragma unroll
    for (int mt = 0; mt < 4; ++mt)
      a[mt] = *(const s16x8*)(lds + aoff + (16 * mt + l15) * RS + 64 * ks + 16 * l4);
#pragma unroll
    for (int nt = 0; nt < 2; ++nt) {
      s16x8 b = Bf[(nt * 8 + ks) * 64];
#pragma unroll
      for (int mt = 0; mt < 4; ++mt) acc[mt][nt] = MFMA16(a[mt], b, acc[mt][nt]);
    }
  }
}

__global__ __launch_bounds__(512, 2) void fused_kernel(
    const float* __restrict__ x, const float* __restrict__ tsg,
    const float* __restrict__ gamma, const float* __restrict__ beta,
    const float* __restrict__ bq, const char* __restrict__ ws,
    float* __restrict__ out) {
  extern __shared__ __align__(16) char lds[];
  const int tid = threadIdx.x;
  const int lane = tid & 63;
  const int w = tid >> 6;           // wave 0..7 == head 0..7
  const int l15 = lane & 15, l4 = lane >> 4;
  const int blk = blockIdx.x;       // covers rows [blk*64, blk*64+64) of (BN*T, C)

  // ---------------- Phase 0: load x + LayerNorm -> h (bf16, LDS) ----------------
  {
    const int r = tid >> 3;    // 0..63 local row
    const int sub = tid & 7;   // 8 threads per row, 32 cols each
    const float* xr = x + ((size_t)blk * 64 + r) * 256 + sub * 32;
    float4 xv[8];
    float s = 0.f, s2 = 0.f;
#pragma unroll
    for (int u = 0; u < 8; ++u) {
      xv[u] = *(const float4*)(xr + 4 * u);
      s  += xv[u].x + xv[u].y + xv[u].z + xv[u].w;
      s2 += xv[u].x * xv[u].x + xv[u].y * xv[u].y + xv[u].z * xv[u].z + xv[u].w * xv[u].w;
    }
#pragma unroll
    for (int m = 1; m <= 4; m <<= 1) { s += __shfl_xor(s, m); s2 += __shfl_xor(s2, m); }
    float mu = s * (1.f / 256.f);
    float rstd = rsqrtf(s2 * (1.f / 256.f) - mu * mu + 1e-5f);
#pragma unroll
    for (int u = 0; u < 8; ++u) {
      int c = sub * 32 + 4 * u;
      float4 gv = *(const float4*)(gamma + c);
      float4 bv = *(const float4*)(beta + c);
      us16x4 hb;
      hb[0] = (unsigned short)f2bf((xv[u].x - mu) * rstd * gv.x + bv.x);
      hb[1] = (unsigned short)f2bf((xv[u].y - mu) * rstd * gv.y + bv.y);
      hb[2] = (unsigned short)f2bf((xv[u].z - mu) * rstd * gv.z + bv.z);
      hb[3] = (unsigned short)f2bf((xv[u].w - mu) * rstd * gv.w + bv.w);
      *(us16x4*)(lds + LDS_H + r * RS + 2 * c) = hb;
    }
    if (tid < 32) ((float*)(lds + LDS_TS))[tid] = tsg[(blk >> 9) * 32 + tid];
  }
  __syncthreads();

  // ---------------- Phase 1: fused Q,K,V,G GEMMs (shared A-frags) ----------------
  float bqv0 = bq[32 * w + l15], bqv1 = bq[32 * w + 16 + l15];
  f32x4 acc[4][4][2];  // [gm][mt][nt]; gm: 0=q 1=k 2=v 3=g
#pragma unroll
  for (int gm = 0; gm < 4; ++gm)
#pragma unroll
    for (int mt = 0; mt < 4; ++mt)
#pragma unroll
      for (int nt = 0; nt < 2; ++nt) acc[gm][mt][nt] = (f32x4){0.f, 0.f, 0.f, 0.f};
  {
    const s16x8* Bq = (const s16x8*)(ws + WS_WQ) + (2 * w * 8) * 64 + lane;
    const s16x8* Bk = (const s16x8*)(ws + WS_WK) + (2 * w * 8) * 64 + lane;
    const s16x8* Bv = (const s16x8*)(ws + WS_WV) + (2 * w * 8) * 64 + lane;
    const s16x8* Bg = (const s16x8*)(ws + WS_WG) + (2 * w * 8) * 64 + lane;
#pragma unroll
    for (int ks = 0; ks < 8; ++ks) {
      s16x8 a[4];
#pragma unroll
      for (int mt = 0; mt < 4; ++mt)
        a[mt] = *(const s16x8*)(lds + LDS_H + (16 * mt + l15) * RS + 64 * ks + 16 * l4);
#pragma unroll
      for (int nt = 0; nt < 2; ++nt) {
        s16x8 b0 = Bq[(nt * 8 + ks) * 64];
        s16x8 b1 = Bk[(nt * 8 + ks) * 64];
        s16x8 b2 = Bv[(nt * 8 + ks) * 64];
        s16x8 b3 = Bg[(nt * 8 + ks) * 64];
#pragma unroll
        for (int mt = 0; mt < 4; ++mt) {
          acc[0][mt][nt] = MFMA16(a[mt], b0, acc[0][mt][nt]);
          acc[1][mt][nt] = MFMA16(a[mt], b1, acc[1][mt][nt]);
          acc[2][mt][nt] = MFMA16(a[mt], b2, acc[2][mt][nt]);
          acc[3][mt][nt] = MFMA16(a[mt], b3, acc[3][mt][nt]);
        }
      }
    }
  }
  // Epilogues. D layout: row = 16*mt + 4*l4 + r, col j = 32*w + 16*nt + l15.
#pragma unroll
  for (int mt = 0; mt < 4; ++mt)
#pragma unroll
    for (int nt = 0; nt < 2; ++nt)
#pragma unroll
      for (int r = 0; r < 4; ++r) {
        int row = 16 * mt + 4 * l4 + r;
        int j = 32 * w + 16 * nt + l15;
        float qv = (acc[0][mt][nt][r] + (nt ? bqv1 : bqv0)) * 0.17677669529663687f;
        *(short*)(lds + LDS_Q + row * RS + 2 * j) = f2bf(qv);              // q (scaled)
        *(short*)(lds + LDS_K + row * RS + 2 * j) = f2bf(acc[1][mt][nt][r]); // k
        *(short*)(lds + LDS_VT + (row >> 5) * 20480 + j * VTS + 2 * (row & 31)) =
            f2bf(acc[2][mt][nt][r]);                                        // v transposed
        acc[3][mt][nt][r] = 1.f / (1.f + __expf(-acc[3][mt][nt][r]));       // g stays in regs
      }
  __syncthreads();  // h dead (P overlays it); q/k/vT published (wave-local anyway)

  // ---------------- Phase 2: attention, one head per wave ----------------
  const float lamh = ((const float*)(ws + WS_LAM))[w];
  const float* tsl = (const float*)(lds + LDS_TS);
  float tc0 = tsl[l15], tc1 = tsl[l15 + 16];
  float trow[8];
#pragma unroll
  for (int mt = 0; mt < 2; ++mt)
#pragma unroll
    for (int r = 0; r < 4; ++r) trow[mt * 4 + r] = tsl[4 * l4 + r + 16 * mt];

#pragma unroll
  for (int half = 0; half < 2; ++half) {
    const int rb = 32 * half;
    const f32x4 zf = {0.f, 0.f, 0.f, 0.f};
    s16x8 aq[2], bk[2];
#pragma unroll
    for (int mt = 0; mt < 2; ++mt)
      aq[mt] = *(const s16x8*)(lds + LDS_Q + (rb + 16 * mt + l15) * RS + 64 * w + 16 * l4);
#pragma unroll
    for (int nt = 0; nt < 2; ++nt)
      bk[nt] = *(const s16x8*)(lds + LDS_K + (rb + 16 * nt + l15) * RS + 64 * w + 16 * l4);
    f32x4 sc[2][2];
#pragma unroll
    for (int mt = 0; mt < 2; ++mt)
#pragma unroll
      for (int nt = 0; nt < 2; ++nt) sc[mt][nt] = MFMA16(aq[mt], bk[nt], zf);

    // bias + softmax over s (cols: 16 lanes x 2 nt), rows in regs
#pragma unroll
    for (int mt = 0; mt < 2; ++mt)
#pragma unroll
      for (int r = 0; r < 4; ++r) {
        float a0 = sc[mt][0][r] - lamh * fabsf(trow[mt * 4 + r] - tc0);
        float a1 = sc[mt][1][r] - lamh * fabsf(trow[mt * 4 + r] - tc1);
        float m = fmaxf(a0, a1);
        m = fmaxf(m, __shfl_xor(m, 1)); m = fmaxf(m, __shfl_xor(m, 2));
        m = fmaxf(m, __shfl_xor(m, 4)); m = fmaxf(m, __shfl_xor(m, 8));
        float e0 = __expf(a0 - m), e1 = __expf(a1 - m);
        float sum = e0 + e1;
        sum += __shfl_xor(sum, 1); sum += __shfl_xor(sum, 2);
        sum += __shfl_xor(sum, 4); sum += __shfl_xor(sum, 8);
        float inv = 1.0f / sum;
        int t = 4 * l4 + r + 16 * mt;
        *(short*)(lds + w * 2560 + t * VTS + 2 * l15)        = f2bf(e0 * inv);
        *(short*)(lds + w * 2560 + t * VTS + 2 * (l15 + 16)) = f2bf(e1 * inv);
      }
    asm volatile("s_waitcnt lgkmcnt(0)" ::: "memory");

    // PV: o[t][d] = sum_s P[t][s] * V[s][d]
    s16x8 ap[2], bv[2];
#pragma unroll
    for (int mt = 0; mt < 2; ++mt)
      ap[mt] = *(const s16x8*)(lds + w * 2560 + (16 * mt + l15) * VTS + 16 * l4);
#pragma unroll
    for (int nd = 0; nd < 2; ++nd)
      bv[nd] = *(const s16x8*)(lds + LDS_VT + half * 20480 +
                               (32 * w + 16 * nd + l15) * VTS + 16 * l4);
#pragma unroll
    for (int mt = 0; mt < 2; ++mt)
#pragma unroll
      for (int nd = 0; nd < 2; ++nd) {
        f32x4 oa = MFMA16(ap[mt], bv[nd], zf);
#pragma unroll
        for (int r = 0; r < 4; ++r) {
          // g-register D-layout matches o D-layout exactly (same tile geometry)
          float go = oa[r] * acc[3][2 * half + mt][nd][r];
          int row = rb + 16 * mt + 4 * l4 + r;
          int j = 32 * w + 16 * nd + l15;
          *(short*)(lds + LDS_Q + row * RS + 2 * j) = f2bf(go);  // reuse q buffer for g*o
        }
      }
    asm volatile("s_waitcnt lgkmcnt(0)" ::: "memory");  // P buffer reused next half
  }
  __syncthreads();

  // ---------------- Phase 3: out = x + (g*o) @ Wo^T ----------------
  {
    f32x4 facc[4][2];
#pragma unroll
    for (int mt = 0; mt < 4; ++mt)
#pragma unroll
      for (int nt = 0; nt < 2; ++nt) facc[mt][nt] = (f32x4){0.f, 0.f, 0.f, 0.f};
    gemm32(lds, LDS_Q, ws + WS_WO, w, lane, facc);
#pragma unroll
    for (int mt = 0; mt < 4; ++mt)
#pragma unroll
      for (int nt = 0; nt < 2; ++nt)
#pragma unroll
        for (int r = 0; r < 4; ++r) {
          int row = 16 * mt + 4 * l4 + r;
          int j = 32 * w + 16 * nt + l15;
          size_t gi = ((size_t)blk * 64 + row) * 256 + j;
          out[gi] = facc[mt][nt][r] + x[gi];  // residual; x is L2-hot
        }
  }
}

extern "C" void kernel_launch(void* const* d_in, const int* in_sizes, int n_in,
                              void* d_out, int out_size, void* d_ws, size_t ws_size,
                              hipStream_t stream) {
  const float* x     = (const float*)d_in[0];
  const float* ts    = (const float*)d_in[1];
  // d_in[2] = n_spatial (=1024, compile-time constant here)
  const float* gamma = (const float*)d_in[3];
  const float* beta  = (const float*)d_in[4];
  const float* Wq    = (const float*)d_in[5];
  const float* bq    = (const float*)d_in[6];
  const float* Wk    = (const float*)d_in[7];
  const float* Wv    = (const float*)d_in[8];
  const float* Wg    = (const float*)d_in[9];
  const float* Wo    = (const float*)d_in[10];
  const float* ll    = (const float*)d_in[11];
  char* ws   = (char*)d_ws;
  float* out = (float*)d_out;

  prep_kernel<<<161, 256, 0, stream>>>(Wq, Wk, Wv, Wg, Wo, ll, ws);

  (void)hipFuncSetAttribute((const void*)fused_kernel,
                            hipFuncAttributeMaxDynamicSharedMemorySize, LDS_TOTAL);
  fused_kernel<<<2048, 512, LDS_TOTAL, stream>>>(x, ts, gamma, beta, bq, ws, out);
}